// Round 1
// baseline (1182.655 us; speedup 1.0000x reference)
//
#include <hip/hip_runtime.h>
#include <hip/hip_bf16.h>
#include <cstdint>
#include <cstddef>

typedef __attribute__((ext_vector_type(4))) float floatx4;
typedef __attribute__((ext_vector_type(8))) __bf16 bf16x8;

#define BS 8
#define SEQ 2048
#define M_TOT 16384
#define DK 4096
#define DN 4096
#define NSK 8
#define RANK 16

__device__ __forceinline__ unsigned short f2bf(float f) {
  union { __hip_bfloat16 h; unsigned short u; } v;
  v.h = __float2bfloat16(f);
  return v.u;
}

// async 16B global->LDS (wave-uniform LDS base + lane*16)
__device__ __forceinline__ void async16(const void* g, void* l) {
  __builtin_amdgcn_global_load_lds(
      (const __attribute__((address_space(1))) unsigned int*)g,
      (__attribute__((address_space(3))) unsigned int*)l, 16, 0, 0);
}

// ---------------------------------------------------------------------------
// 1. Mixing weights: mw[b][s] = sigmoid(logits[task[b]][s]) normalized per b.
//    task_ids may be int64 (per reference) or int32 (jax x64 disabled) — sniff.
__global__ void prep_mw_kernel(const float* __restrict__ logits,
                               const void* __restrict__ task_raw,
                               float* __restrict__ mw) {
  const int* t32 = (const int*)task_raw;
  bool is64 = true;
#pragma unroll
  for (int b = 0; b < BS; ++b)
    if (t32[2 * b + 1] != 0) is64 = false;  // high words nonzero => int32 data
  int tid = threadIdx.x;        // 64 threads: 8 batches x 8 skills
  int b = tid >> 3, s = tid & 7;
  int task = is64 ? t32[2 * b] : t32[b];
  float lg = logits[task * NSK + s];
  float sg = 1.0f / (1.0f + expf(-lg));
  float sum = sg;
  sum += __shfl_xor(sum, 1);
  sum += __shfl_xor(sum, 2);
  sum += __shfl_xor(sum, 4);
  mw[tid] = sg / (sum + 1e-12f);
}

// ---------------------------------------------------------------------------
// 2a. A_bfT[b][r][d] = bf16( sum_s mw[b][s] * lora_a[s][d][r] )   (16 x 4096)
__global__ __launch_bounds__(256) void prep_a_kernel(
    const float* __restrict__ lora_a, const float* __restrict__ mw,
    unsigned short* __restrict__ a_bft) {
  int b = blockIdx.y;
  int d = blockIdx.x * 256 + threadIdx.x;
  float w[NSK];
#pragma unroll
  for (int s = 0; s < NSK; ++s) w[s] = mw[b * NSK + s];
  float acc[RANK];
#pragma unroll
  for (int r = 0; r < RANK; ++r) acc[r] = 0.f;
  for (int s = 0; s < NSK; ++s) {
    const float4* p = (const float4*)&lora_a[((size_t)s * DK + d) * RANK];
#pragma unroll
    for (int q = 0; q < 4; ++q) {
      float4 v = p[q];
      acc[q * 4 + 0] += w[s] * v.x;
      acc[q * 4 + 1] += w[s] * v.y;
      acc[q * 4 + 2] += w[s] * v.z;
      acc[q * 4 + 3] += w[s] * v.w;
    }
  }
#pragma unroll
  for (int r = 0; r < RANK; ++r)
    a_bft[((size_t)b * RANK + r) * DK + d] = f2bf(acc[r]);
}

// 2b. baug[b][n][0..31]: r<16 -> bf16( (sum_s mw*lora_b[s][r][n]) / 16 ), else 0
__global__ __launch_bounds__(256) void prep_b_kernel(
    const float* __restrict__ lora_b, const float* __restrict__ mw,
    unsigned short* __restrict__ baug) {
  int b = blockIdx.y;
  int n = blockIdx.x * 256 + threadIdx.x;
  float w[NSK];
#pragma unroll
  for (int s = 0; s < NSK; ++s) w[s] = mw[b * NSK + s];
  unsigned short ov[32];
#pragma unroll
  for (int r = 0; r < RANK; ++r) {
    float acc = 0.f;
#pragma unroll
    for (int s = 0; s < NSK; ++s)
      acc += w[s] * lora_b[((size_t)s * RANK + r) * DN + n];
    ov[r] = f2bf(acc * 0.0625f);  // fold the /rank here
  }
#pragma unroll
  for (int r = RANK; r < 32; ++r) ov[r] = 0;
  uint4* dst = (uint4*)&baug[((size_t)b * DN + n) * 32];
  const uint4* sv = (const uint4*)ov;
  dst[0] = sv[0]; dst[1] = sv[1]; dst[2] = sv[2]; dst[3] = sv[3];
}

// ---------------------------------------------------------------------------
// 3. fp32 -> bf16 bulk conversion (float4 in, ushort4 out), grid-stride
__global__ __launch_bounds__(256) void conv_f32_to_bf16(
    const float* __restrict__ src, unsigned short* __restrict__ dst,
    long long n4) {
  long long stride = (long long)gridDim.x * 256;
  for (long long i = (long long)blockIdx.x * 256 + threadIdx.x; i < n4; i += stride) {
    float4 v = ((const float4*)src)[i];
    ushort4 o;
    o.x = f2bf(v.x); o.y = f2bf(v.y); o.z = f2bf(v.z); o.w = f2bf(v.w);
    ((ushort4*)dst)[i] = o;
  }
}

// ---------------------------------------------------------------------------
// 4. t[16384][16] = xb @ A_bfT^T via MFMA, K split 4 ways, fp32 atomics.
//    One wave = one 16-row tile. B-frag lane n=lane&15 needs B[k][n]=A_mix[k][n]
//    = a_bft[n][k], contiguous in k. C/D layout: col=lane&15, row=quad*4+reg.
__global__ __launch_bounds__(256) void t_gemm_kernel(
    const unsigned short* __restrict__ xb, const unsigned short* __restrict__ abft,
    float* __restrict__ t_f32) {
  const int wave = threadIdx.x >> 6;
  const int lane = threadIdx.x & 63;
  const int mtile = blockIdx.x * 4 + wave;  // 0..1023
  const int row0 = mtile * 16;
  const int b = row0 >> 11;                 // /2048
  const int k0 = blockIdx.y * 1024;
  const int fr = lane & 15;
  const int fq = (lane >> 4) * 8;
  const unsigned short* pa = xb + (size_t)(row0 + fr) * DK + fq + k0;
  const unsigned short* pb = abft + ((size_t)b * RANK + fr) * DK + fq + k0;
  floatx4 acc = {0.f, 0.f, 0.f, 0.f};
  for (int k = 0; k < 1024; k += 32) {
    bf16x8 av = *(const bf16x8*)(pa + k);
    bf16x8 bv = *(const bf16x8*)(pb + k);
    acc = __builtin_amdgcn_mfma_f32_16x16x32_bf16(av, bv, acc, 0, 0, 0);
  }
  const int col = lane & 15;
  const int rowq = (lane >> 4) * 4;
#pragma unroll
  for (int j = 0; j < 4; ++j)
    atomicAdd(&t_f32[(size_t)(row0 + rowq + j) * RANK + col], acc[j]);
}

// 5. taug[row][0..31]: r<16 -> bf16(t), else 0
__global__ __launch_bounds__(256) void t_final_kernel(
    const float* __restrict__ t_f32, unsigned short* __restrict__ taug) {
  int i = blockIdx.x * 256 + threadIdx.x;  // 262144 total
  int row = i >> 4, r = i & 15;
  taug[(size_t)row * 32 + r] = f2bf(t_f32[i]);
  taug[(size_t)row * 32 + 16 + r] = 0;
}

// ---------------------------------------------------------------------------
// 6. Main GEMM (m97 structure): out = xb @ wb^T + bias, K=4096 plus one
//    augmented K-step (k=4096..4127) sourcing A from taug and B from baug[batch]
//    which adds the adapter (x@A)@B/16. 128x128 tile, BK=32, 4 waves 2x2,
//    global_load_lds width-16 staging, 16x16x32 bf16 MFMA, 4x4 tiles/wave.
__global__ __launch_bounds__(256) void main_gemm(
    const unsigned short* __restrict__ xb, const unsigned short* __restrict__ wb,
    const unsigned short* __restrict__ taug, const unsigned short* __restrict__ baug,
    const float* __restrict__ bias, float* __restrict__ out) {
  __shared__ __align__(16) unsigned short sA[128 * 32];
  __shared__ __align__(16) unsigned short sB[128 * 32];
  const int tid = threadIdx.x;
  const int wave = tid >> 6;
  const int lane = tid & 63;
  const int bx = blockIdx.x, by = blockIdx.y;
  const int m0 = by * 128, n0 = bx * 128;
  const int batch = by >> 4;  // 128 rows/block, 2048 rows/batch -> 16 blocks/batch

  // staging: chunk c (c=wave, wave+4) covers LDS rows [c*16, c*16+16), 64B/row
  const int srow = lane >> 2;        // row within chunk
  const int skk = (lane & 3) * 8;    // bf16 k-offset within row
  const int rA0 = wave * 16 + srow;
  const int rA1 = rA0 + 64;
  const unsigned short* gA0 = xb + (size_t)(m0 + rA0) * DK + skk;
  const unsigned short* gA1 = xb + (size_t)(m0 + rA1) * DK + skk;
  const unsigned short* gB0 = wb + (size_t)(n0 + rA0) * DK + skk;
  const unsigned short* gB1 = wb + (size_t)(n0 + rA1) * DK + skk;
  const unsigned short* gA0x = taug + (size_t)(m0 + rA0) * 32 + skk;
  const unsigned short* gA1x = taug + (size_t)(m0 + rA1) * 32 + skk;
  const unsigned short* gB0x = baug + ((size_t)batch * DN + n0 + rA0) * 32 + skk;
  const unsigned short* gB1x = baug + ((size_t)batch * DN + n0 + rA1) * 32 + skk;
  unsigned short* lA0 = sA + wave * 512;        // 512 ushort = 1024 B chunk
  unsigned short* lA1 = sA + (wave + 4) * 512;
  unsigned short* lB0 = sB + wave * 512;
  unsigned short* lB1 = sB + (wave + 4) * 512;

  floatx4 acc[4][4];
#pragma unroll
  for (int i = 0; i < 4; ++i)
#pragma unroll
    for (int j = 0; j < 4; ++j) acc[i][j] = (floatx4){0.f, 0.f, 0.f, 0.f};

  const int wm = (wave >> 1) * 64;  // wave 2x2 -> 64x64 subtile
  const int wn = (wave & 1) * 64;
  const int fr = lane & 15;
  const int fq = (lane >> 4) * 8;

  for (int s = 0; s < 129; ++s) {
    __syncthreads();  // previous iteration's LDS reads complete
    if (s < 128) {
      const int k0 = s * 32;
      async16(gA0 + k0, lA0);
      async16(gA1 + k0, lA1);
      async16(gB0 + k0, lB0);
      async16(gB1 + k0, lB1);
    } else {  // augmented step: adapter
      async16(gA0x, lA0);
      async16(gA1x, lA1);
      async16(gB0x, lB0);
      async16(gB1x, lB1);
    }
    __syncthreads();  // compiler drains vmcnt before s_barrier

    bf16x8 av[4], bv[4];
#pragma unroll
    for (int t = 0; t < 4; ++t) {
      av[t] = *(const bf16x8*)&sA[(wm + t * 16 + fr) * 32 + fq];
      bv[t] = *(const bf16x8*)&sB[(wn + t * 16 + fr) * 32 + fq];
    }
#pragma unroll
    for (int tm = 0; tm < 4; ++tm)
#pragma unroll
      for (int tn = 0; tn < 4; ++tn)
        acc[tm][tn] = __builtin_amdgcn_mfma_f32_16x16x32_bf16(av[tm], bv[tn],
                                                              acc[tm][tn], 0, 0, 0);
  }

  // epilogue: C/D layout col=lane&15, row=(lane>>4)*4+reg; add bias
  const int colt = lane & 15;
  const int rowq = (lane >> 4) * 4;
#pragma unroll
  for (int tn = 0; tn < 4; ++tn) {
    const int col = n0 + wn + tn * 16 + colt;
    const float bvv = bias[col];
#pragma unroll
    for (int tm = 0; tm < 4; ++tm) {
      const size_t row = (size_t)(m0 + wm + tm * 16 + rowq);
      float* po = out + row * DN + col;
#pragma unroll
      for (int j = 0; j < 4; ++j) po[(size_t)j * DN] = acc[tm][tn][j] + bvv;
    }
  }
}

// ---------------------------------------------------------------------------
extern "C" void kernel_launch(void* const* d_in, const int* in_sizes, int n_in,
                              void* d_out, int out_size, void* d_ws, size_t ws_size,
                              hipStream_t stream) {
  (void)in_sizes; (void)n_in; (void)out_size; (void)ws_size;
  const float* x             = (const float*)d_in[0];
  const float* weight        = (const float*)d_in[1];
  const float* bias          = (const float*)d_in[2];
  const float* module_logits = (const float*)d_in[3];
  const float* lora_a        = (const float*)d_in[4];
  const float* lora_b        = (const float*)d_in[5];
  const void*  task_ids      = d_in[6];
  float* out = (float*)d_out;

  // workspace layout (all 16B-aligned); total ~165 MB
  char* ws = (char*)d_ws;
  unsigned short* xb   = (unsigned short*)(ws);                  // 16384*4096*2 = 134217728
  unsigned short* wb   = (unsigned short*)(ws + 134217728);      // 4096*4096*2  = 33554432
  unsigned short* taug = (unsigned short*)(ws + 167772160);      // 16384*32*2   = 1048576
  unsigned short* baug = (unsigned short*)(ws + 168820736);      // 8*4096*32*2  = 2097152
  unsigned short* abft = (unsigned short*)(ws + 170917888);      // 8*16*4096*2  = 1048576
  float*          tf32 = (float*)(ws + 171966464);               // 16384*16*4   = 1048576
  float*          mw   = (float*)(ws + 173015040);               // 256

  hipLaunchKernelGGL(prep_mw_kernel, dim3(1), dim3(64), 0, stream,
                     module_logits, task_ids, mw);
  hipLaunchKernelGGL(prep_a_kernel, dim3(16, 8), dim3(256), 0, stream,
                     lora_a, mw, abft);
  hipLaunchKernelGGL(prep_b_kernel, dim3(16, 8), dim3(256), 0, stream,
                     lora_b, mw, baug);
  hipLaunchKernelGGL(conv_f32_to_bf16, dim3(2048), dim3(256), 0, stream,
                     weight, wb, (long long)(4096LL * 4096 / 4));
  hipLaunchKernelGGL(conv_f32_to_bf16, dim3(8192), dim3(256), 0, stream,
                     x, xb, (long long)(16384LL * 4096 / 4));
  hipMemsetAsync(tf32, 0, (size_t)M_TOT * RANK * sizeof(float), stream);
  hipLaunchKernelGGL(t_gemm_kernel, dim3(256, 4), dim3(256), 0, stream,
                     xb, abft, tf32);
  hipLaunchKernelGGL(t_final_kernel, dim3(1024), dim3(256), 0, stream,
                     tf32, taug);
  hipLaunchKernelGGL(main_gemm, dim3(32, 128), dim3(256), 0, stream,
                     xb, wb, taug, baug, bias, out);
}